// Round 10
// baseline (377.070 us; speedup 1.0000x reference)
//
#include <hip/hip_runtime.h>
#include <hip/hip_bf16.h>
#include <hip/hip_fp16.h>
#include <math.h>

// MoNet / GMMConv 2-layer GNN on MI355X (gfx950).
// R10: R9 skeleton; z1/edge2 inner loops converted from rotation-prefetch to
// software-pipelined dual-buffer (ping-pong) form -> zero v_mov rotation.
// Sentinel padding extended to 4. Everything else unchanged from R9.

#define NF 128
#define NH 64
#define NC 16
#define Z1NODES 16
#define Z1CAP 448
#define E2NODES 16
#define E2CAP 320
#define GXST 160   // gx2e row stride in ushorts (144 cols + pad, 320B rows)

typedef __bf16 v8bf __attribute__((ext_vector_type(8)));
typedef float v4f __attribute__((ext_vector_type(4)));

__device__ inline ushort f2bu(float x) {
  __hip_bfloat16 h = __float2bfloat16(x);
  return *(ushort*)&h;
}
__device__ inline uint packh2(float a, float b) {
  __half ha = __float2half_rn(a), hb = __float2half_rn(b);
  return (uint)(*(ushort*)&ha) | ((uint)(*(ushort*)&hb) << 16);
}
__device__ inline float2 unph2(uint u) {
  ushort a = (ushort)(u & 0xffff), b = (ushort)(u >> 16);
  return make_float2(__half2float(*(__half*)&a), __half2float(*(__half*)&b));
}
__device__ inline v8bf ld_frag(const ushort* p) {
  uint4 u = *(const uint4*)p;
  return __builtin_bit_cast(v8bf, u);
}

// ---------------- CSR build (verified) ----------------
__global__ __launch_bounds__(256) void hist_kernel(const int* __restrict__ col,
                                                   int* __restrict__ counts, int E) {
  int e = blockIdx.x * 256 + threadIdx.x;
  if (e < E) atomicAdd(&counts[col[e]], 1);
}

__global__ __launch_bounds__(256) void scan1_kernel(const int* __restrict__ counts,
                                                    int* __restrict__ starts,
                                                    int* __restrict__ bsums) {
  __shared__ int wsum[4];
  const int t = threadIdx.x, lane = t & 63, wv = t >> 6;
  int4 v = ((const int4*)counts)[blockIdx.x * 256 + t];
  int tsum = v.x + v.y + v.z + v.w;
  int inc = tsum;
  #pragma unroll
  for (int off = 1; off < 64; off <<= 1) {
    int u = __shfl_up(inc, off, 64);
    if (lane >= off) inc += u;
  }
  if (lane == 63) wsum[wv] = inc;
  __syncthreads();
  int wpre = 0;
  for (int j = 0; j < wv; ++j) wpre += wsum[j];
  int excl = wpre + inc - tsum;
  int4 o;
  o.x = excl; o.y = o.x + v.x; o.z = o.y + v.y; o.w = o.z + v.z;
  ((int4*)starts)[blockIdx.x * 256 + t] = o;
  if (t == 255) bsums[blockIdx.x] = excl + tsum;
}

__global__ __launch_bounds__(64) void scan2_kernel(const int* __restrict__ bsums,
                                                   int* __restrict__ bofs, int NB) {
  int lane = threadIdx.x;
  int v = (lane < NB) ? bsums[lane] : 0;
  int inc = v;
  #pragma unroll
  for (int off = 1; off < 64; off <<= 1) {
    int u = __shfl_up(inc, off, 64);
    if (lane >= off) inc += u;
  }
  if (lane < NB) bofs[lane] = inc - v;
}

__global__ __launch_bounds__(256) void scan3_kernel(int* __restrict__ starts,
                                                    int* __restrict__ cursor,
                                                    const int* __restrict__ bofs) {
  int add = bofs[blockIdx.x];
  int idx = blockIdx.x * 256 + threadIdx.x;
  int4 s = ((int4*)starts)[idx];
  s.x += add; s.y += add; s.z += add; s.w += add;
  ((int4*)starts)[idx] = s;
  ((int4*)cursor)[idx] = s;
}

__global__ __launch_bounds__(256) void fill_kernel(
    const int* __restrict__ row, const int* __restrict__ col,
    const float* __restrict__ eattr,
    const float* __restrict__ mu1, const float* __restrict__ sg1,
    const float* __restrict__ mu2, const float* __restrict__ sg2,
    int* __restrict__ cursor, int* __restrict__ erow,
    uint4* __restrict__ ew1, uint4* __restrict__ ew2, int E) {
  int e = blockIdx.x * 256 + threadIdx.x;
  if (e >= E) return;
  int c = col[e];
  int pos = atomicAdd(&cursor[c], 1);
  float p0 = eattr[2 * e], p1 = eattr[2 * e + 1];
  float w1[8], w2[8];
  #pragma unroll
  for (int k = 0; k < 8; ++k) {
    float d0 = p0 - mu1[2 * k], d1 = p1 - mu1[2 * k + 1];
    float s0 = sg1[2 * k], s1 = sg1[2 * k + 1];
    w1[k] = __expf(-0.5f * (d0 * d0 / (1e-15f + s0 * s0) +
                            d1 * d1 / (1e-15f + s1 * s1)));
    float e0 = p0 - mu2[2 * k], e1 = p1 - mu2[2 * k + 1];
    float t0 = sg2[2 * k], t1 = sg2[2 * k + 1];
    w2[k] = __expf(-0.5f * (e0 * e0 / (1e-15f + t0 * t0) +
                            e1 * e1 / (1e-15f + t1 * t1)));
  }
  erow[pos] = row[e];
  ew1[pos] = make_uint4(packh2(w1[0], w1[1]), packh2(w1[2], w1[3]),
                        packh2(w1[4], w1[5]), packh2(w1[6], w1[7]));
  ew2[pos] = make_uint4(packh2(w2[0], w2[1]), packh2(w2[2], w2[3]),
                        packh2(w2[4], w2[5]), packh2(w2[6], w2[7]));
}

__global__ __launch_bounds__(256) void cast_x_kernel(const float* __restrict__ x,
                                                     ushort* __restrict__ A1, int N) {
  int idx = blockIdx.x * 256 + threadIdx.x;
  if (idx >= N * 32) return;
  int n = idx >> 5, c4 = idx & 31;
  float4 v = ((const float4*)x)[idx];
  ushort4 o;
  o.x = f2bu(v.x); o.y = f2bu(v.y); o.z = f2bu(v.z); o.w = f2bu(v.w);
  *(ushort4*)(A1 + (size_t)n * 1152 + 1024 + c4 * 4) = o;
}

// ---- prep: W1t [64][1152]; G2pT [144][64] permuted [g2w|r2w] ----
__global__ __launch_bounds__(256) void prep_kernel(
    const float* __restrict__ g1w, const float* __restrict__ r1w,
    const float* __restrict__ g2w, const float* __restrict__ r2w,
    ushort* __restrict__ W1t, ushort* __restrict__ G2pT) {
  int i = blockIdx.x * 256 + threadIdx.x;
  if (i < 64 * 1152) {
    int h = i / 1152, j = i % 1152;
    float v = (j < 1024) ? g1w[(size_t)(j & 127) * 512 + (j >> 7) * 64 + h]
                         : r1w[(size_t)(j - 1024) * 64 + h];
    W1t[i] = f2bu(v);
  } else {
    int i2 = i - 64 * 1152;
    if (i2 < 144 * 64) {
      int cp = i2 / 64, f = i2 % 64;
      float v;
      if (cp < 128) {
        int kq = cp >> 5, rem = cp & 31;
        int o = rem >> 1, k = kq * 2 + (rem & 1);
        v = g2w[(size_t)f * 128 + k * 16 + o];
      } else {
        v = r2w[(size_t)f * 16 + (cp - 128)];
      }
      G2pT[i2] = f2bu(v);
    }
  }
}

// ======= z1 v3: Z[n,k*128+f] = (1/deg) sum w_ek x_bf[r,f] =======
// Software-pipelined ping-pong (no register rotation), sentinels x4.
__global__ __launch_bounds__(256) void z1_kernel(
    ushort* __restrict__ A1, const int* __restrict__ erow,
    const uint4* __restrict__ ew1, const int* __restrict__ starts, int N) {
  __shared__ __align__(16) float lw[Z1CAP + 4][8];
  __shared__ int loff[Z1CAP + 4];
  const int t = threadIdx.x, lane = t & 63, wv = t >> 6;
  const int base = (int)blockIdx.x * Z1NODES;
  const int S = starts[base];
  const int cl = min(starts[base + Z1NODES] - S, Z1CAP);
  for (int i = t; i < cl; i += 256) {
    loff[i] = erow[S + i] * 2304;          // byte offset of row
    uint4 q = ew1[S + i];
    float2 a = unph2(q.x), b = unph2(q.y), c = unph2(q.z), d = unph2(q.w);
    *(float4*)&lw[i][0] = make_float4(a.x, a.y, b.x, b.y);
    *(float4*)&lw[i][4] = make_float4(c.x, c.y, d.x, d.y);
  }
  if (t < 4) {
    loff[cl + t] = 0;
    *(float4*)&lw[cl + t][0] = make_float4(0.f, 0.f, 0.f, 0.f);
    *(float4*)&lw[cl + t][4] = make_float4(0.f, 0.f, 0.f, 0.f);
  }
  __syncthreads();

  const char* xb = (const char*)(A1 + 1024) + (lane << 2);

  for (int i = 0; i < Z1NODES / 4; ++i) {
    const int n = base + wv * 4 + i;
    const int be = starts[n], ee = starts[n + 1];
    float a0[8], a1[8];
    #pragma unroll
    for (int k = 0; k < 8; ++k) { a0[k] = 0.f; a1[k] = 0.f; }

    const int re = min(ee, S + cl);        // end of LDS-window portion
    int j = be;
    if (j < re) {
      int rel = j - S;
      float4 wlA = *(float4*)&lw[rel][0],     whA = *(float4*)&lw[rel][4];
      uint   gA  = *(const uint*)(xb + loff[rel]);
      float4 wlB = *(float4*)&lw[rel + 1][0], whB = *(float4*)&lw[rel + 1][4];
      uint   gB  = *(const uint*)(xb + loff[rel + 1]);
      while (true) {
        // compute slot A (edge j), refill A with edge j+2
        {
          float f0 = __uint_as_float(gA << 16);
          float f1 = __uint_as_float(gA & 0xffff0000u);
          a0[0] = fmaf(wlA.x, f0, a0[0]); a1[0] = fmaf(wlA.x, f1, a1[0]);
          a0[1] = fmaf(wlA.y, f0, a0[1]); a1[1] = fmaf(wlA.y, f1, a1[1]);
          a0[2] = fmaf(wlA.z, f0, a0[2]); a1[2] = fmaf(wlA.z, f1, a1[2]);
          a0[3] = fmaf(wlA.w, f0, a0[3]); a1[3] = fmaf(wlA.w, f1, a1[3]);
          a0[4] = fmaf(whA.x, f0, a0[4]); a1[4] = fmaf(whA.x, f1, a1[4]);
          a0[5] = fmaf(whA.y, f0, a0[5]); a1[5] = fmaf(whA.y, f1, a1[5]);
          a0[6] = fmaf(whA.z, f0, a0[6]); a1[6] = fmaf(whA.z, f1, a1[6]);
          a0[7] = fmaf(whA.w, f0, a0[7]); a1[7] = fmaf(whA.w, f1, a1[7]);
        }
        rel = j - S;
        wlA = *(float4*)&lw[rel + 2][0]; whA = *(float4*)&lw[rel + 2][4];
        gA  = *(const uint*)(xb + loff[rel + 2]);
        if (++j >= re) break;
        // compute slot B (edge j), refill B with edge j+2
        {
          float f0 = __uint_as_float(gB << 16);
          float f1 = __uint_as_float(gB & 0xffff0000u);
          a0[0] = fmaf(wlB.x, f0, a0[0]); a1[0] = fmaf(wlB.x, f1, a1[0]);
          a0[1] = fmaf(wlB.y, f0, a0[1]); a1[1] = fmaf(wlB.y, f1, a1[1]);
          a0[2] = fmaf(wlB.z, f0, a0[2]); a1[2] = fmaf(wlB.z, f1, a1[2]);
          a0[3] = fmaf(wlB.w, f0, a0[3]); a1[3] = fmaf(wlB.w, f1, a1[3]);
          a0[4] = fmaf(whB.x, f0, a0[4]); a1[4] = fmaf(whB.x, f1, a1[4]);
          a0[5] = fmaf(whB.y, f0, a0[5]); a1[5] = fmaf(whB.y, f1, a1[5]);
          a0[6] = fmaf(whB.z, f0, a0[6]); a1[6] = fmaf(whB.z, f1, a1[6]);
          a0[7] = fmaf(whB.w, f0, a0[7]); a1[7] = fmaf(whB.w, f1, a1[7]);
        }
        wlB = *(float4*)&lw[rel + 3][0]; whB = *(float4*)&lw[rel + 3][4];
        gB  = *(const uint*)(xb + loff[rel + 3]);
        if (++j >= re) break;
      }
    }
    for (; j < ee; ++j) {                   // rare global tail
      uint4 q = ew1[j];
      uint g = *(const uint*)(xb + erow[j] * 2304);
      float2 a = unph2(q.x), b = unph2(q.y), c = unph2(q.z), d = unph2(q.w);
      float f0 = __uint_as_float(g << 16);
      float f1 = __uint_as_float(g & 0xffff0000u);
      a0[0] = fmaf(a.x, f0, a0[0]); a1[0] = fmaf(a.x, f1, a1[0]);
      a0[1] = fmaf(a.y, f0, a0[1]); a1[1] = fmaf(a.y, f1, a1[1]);
      a0[2] = fmaf(b.x, f0, a0[2]); a1[2] = fmaf(b.x, f1, a1[2]);
      a0[3] = fmaf(b.y, f0, a0[3]); a1[3] = fmaf(b.y, f1, a1[3]);
      a0[4] = fmaf(c.x, f0, a0[4]); a1[4] = fmaf(c.x, f1, a1[4]);
      a0[5] = fmaf(c.y, f0, a0[5]); a1[5] = fmaf(c.y, f1, a1[5]);
      a0[6] = fmaf(d.x, f0, a0[6]); a1[6] = fmaf(d.x, f1, a1[6]);
      a0[7] = fmaf(d.y, f0, a0[7]); a1[7] = fmaf(d.y, f1, a1[7]);
    }
    const float inv = 1.f / fmaxf((float)(ee - be), 1.f);
    ushort* zr = A1 + (size_t)n * 1152;
    #pragma unroll
    for (int k = 0; k < 8; ++k) {
      uint pk = (uint)f2bu(a0[k] * inv) | ((uint)f2bu(a1[k] * inv) << 16);
      *(uint*)(zr + k * 128 + 2 * lane) = pk;
    }
  }
}

// ---- gemm1 (unchanged R7/R8): h_bf = ELU( A1 @ W1t^T + b1 ), LDS-dbuf ----
__global__ __launch_bounds__(256) void gemm1_mfma(
    const ushort* __restrict__ A1, const ushort* __restrict__ W1t,
    const float* __restrict__ b1, ushort* __restrict__ h_bf, int N) {
  __shared__ __align__(16) ushort As[2][64 * 32];
  __shared__ __align__(16) ushort Bs[2][64 * 32];
  const int t = threadIdx.x, lane = t & 63, wv = t >> 6;
  const int mfrag = lane & 15, quad = lane >> 4;
  const int m0 = (int)blockIdx.x * 64;
  const int st_r = t >> 2, st_c = (t & 3) * 8;
  const int st_o = st_r * 32 + st_c;
  const ushort* ag = A1 + (size_t)(m0 + st_r) * 1152 + st_c;
  const ushort* bg = W1t + (size_t)st_r * 1152 + st_c;

  {
    uint4 a0 = *(const uint4*)ag;
    uint4 b0 = *(const uint4*)bg;
    *(uint4*)(&As[0][st_o]) = a0;
    *(uint4*)(&Bs[0][st_o]) = b0;
  }
  __syncthreads();

  v4f acc[4];
  #pragma unroll
  for (int ct = 0; ct < 4; ++ct) acc[ct] = (v4f){0.f, 0.f, 0.f, 0.f};

  for (int kc = 0; kc < 36; ++kc) {
    const int cb = kc & 1, nb = cb ^ 1;
    uint4 an, bn;
    if (kc < 35) {
      an = *(const uint4*)(ag + (kc + 1) * 32);
      bn = *(const uint4*)(bg + (kc + 1) * 32);
    }
    v8bf a = ld_frag(&As[cb][(wv * 16 + mfrag) * 32 + quad * 8]);
    #pragma unroll
    for (int ct = 0; ct < 4; ++ct) {
      v8bf b = ld_frag(&Bs[cb][(ct * 16 + mfrag) * 32 + quad * 8]);
      acc[ct] = __builtin_amdgcn_mfma_f32_16x16x32_bf16(a, b, acc[ct], 0, 0, 0);
    }
    if (kc < 35) {
      *(uint4*)(&As[nb][st_o]) = an;
      *(uint4*)(&Bs[nb][st_o]) = bn;
      __syncthreads();
    }
  }
  #pragma unroll
  for (int ct = 0; ct < 4; ++ct) {
    const int colh = ct * 16 + mfrag;
    const float bc = b1[colh];
    #pragma unroll
    for (int r = 0; r < 4; ++r) {
      int node = m0 + wv * 16 + quad * 4 + r;
      if (node < N) {
        float v = acc[ct][r] + bc;
        v = v > 0.f ? v : expm1f(v);
        h_bf[(size_t)node * NH + colh] = f2bu(v);
      }
    }
  }
}

// ---- gemm2a (unchanged R8): gx2e[N,160] = bf16( h_bf @ G2pT^T ) ----
__global__ __launch_bounds__(256) void gemm2a_kernel(
    const ushort* __restrict__ h_bf, const ushort* __restrict__ G2pT,
    ushort* __restrict__ gx2e, int N) {
  const int t = threadIdx.x, lane = t & 63, wv = t >> 6;
  const int mfrag = lane & 15, quad = lane >> 4;
  const int m0 = (int)blockIdx.x * 64 + wv * 16;
  v4f acc[9];
  #pragma unroll
  for (int t9 = 0; t9 < 9; ++t9) acc[t9] = (v4f){0.f, 0.f, 0.f, 0.f};
  const ushort* arow = h_bf + (size_t)(m0 + mfrag) * 64 + quad * 8;
  const ushort* brow = G2pT + (size_t)mfrag * 64 + quad * 8;
  #pragma unroll
  for (int kc = 0; kc < 2; ++kc) {
    v8bf a = ld_frag(arow + kc * 32);
    #pragma unroll
    for (int t9 = 0; t9 < 9; ++t9) {
      v8bf b = ld_frag(brow + (size_t)t9 * 16 * 64 + kc * 32);
      acc[t9] = __builtin_amdgcn_mfma_f32_16x16x32_bf16(a, b, acc[t9], 0, 0, 0);
    }
  }
  #pragma unroll
  for (int t9 = 0; t9 < 9; ++t9) {
    #pragma unroll
    for (int r = 0; r < 4; ++r) {
      int node = m0 + quad * 4 + r;
      if (node < N)
        gx2e[(size_t)node * GXST + t9 * 16 + mfrag] = f2bu(acc[t9][r]);
    }
  }
}

// ==== edge2 v3: out = lsm( (sum_e w.gx2e[r])/deg + root + b2 ) ====
// Software-pipelined ping-pong, sentinels x4.
__global__ __launch_bounds__(256) void edge2_kernel(
    const ushort* __restrict__ gx2e, const int* __restrict__ erow,
    const uint4* __restrict__ ew2, const int* __restrict__ starts,
    const float* __restrict__ b2, float* __restrict__ out, int N) {
  __shared__ __align__(16) float lw[E2CAP + 4][8];
  __shared__ int loff[E2CAP + 4];
  __shared__ float lb2[16];
  const int t = threadIdx.x, lane = t & 63, wv = t >> 6;
  const int base = (int)blockIdx.x * E2NODES;
  const int S = starts[base];
  const int cl = min(starts[base + E2NODES] - S, E2CAP);
  if (t < 16) lb2[t] = b2[t];
  for (int i = t; i < cl; i += 256) {
    loff[i] = erow[S + i] * 320;
    uint4 q = ew2[S + i];
    float2 a = unph2(q.x), b = unph2(q.y), c = unph2(q.z), d = unph2(q.w);
    *(float4*)&lw[i][0] = make_float4(a.x, a.y, b.x, b.y);
    *(float4*)&lw[i][4] = make_float4(c.x, c.y, d.x, d.y);
  }
  if (t < 4) {
    loff[cl + t] = 0;
    *(float4*)&lw[cl + t][0] = make_float4(0.f, 0.f, 0.f, 0.f);
    *(float4*)&lw[cl + t][4] = make_float4(0.f, 0.f, 0.f, 0.f);
  }
  __syncthreads();

  const int o = lane & 15, kq = lane >> 4;
  const char* gb = (const char*)gx2e + kq * 64 + o * 4;

  for (int i = 0; i < E2NODES / 4; ++i) {
    const int n = base + wv * 4 + i;
    if (n >= N) continue;
    const int be = starts[n], ee = starts[n + 1];
    float acc0 = 0.f, acc1 = 0.f;
    const int re = min(ee, S + cl);
    int j = be;
    if (j < re) {
      int rel = j - S;
      float2 wA = *(float2*)&lw[rel][kq * 2];
      uint   gA = *(const uint*)(gb + loff[rel]);
      float2 wB = *(float2*)&lw[rel + 1][kq * 2];
      uint   gB = *(const uint*)(gb + loff[rel + 1]);
      while (true) {
        {
          float f0 = __uint_as_float(gA << 16);
          float f1 = __uint_as_float(gA & 0xffff0000u);
          acc0 = fmaf(wA.x, f0, acc0);
          acc1 = fmaf(wA.y, f1, acc1);
        }
        rel = j - S;
        wA = *(float2*)&lw[rel + 2][kq * 2];
        gA = *(const uint*)(gb + loff[rel + 2]);
        if (++j >= re) break;
        {
          float f0 = __uint_as_float(gB << 16);
          float f1 = __uint_as_float(gB & 0xffff0000u);
          acc0 = fmaf(wB.x, f0, acc0);
          acc1 = fmaf(wB.y, f1, acc1);
        }
        wB = *(float2*)&lw[rel + 3][kq * 2];
        gB = *(const uint*)(gb + loff[rel + 3]);
        if (++j >= re) break;
      }
    }
    for (; j < ee; ++j) {                   // rare global tail
      uint4 q = ew2[j];
      uint comp = (kq == 0) ? q.x : (kq == 1) ? q.y : (kq == 2) ? q.z : q.w;
      float2 wp = unph2(comp);
      uint g = *(const uint*)(gb + erow[j] * 320);
      float f0 = __uint_as_float(g << 16);
      float f1 = __uint_as_float(g & 0xffff0000u);
      acc0 = fmaf(wp.x, f0, acc0);
      acc1 = fmaf(wp.y, f1, acc1);
    }
    float s = acc0 + acc1;
    s += __shfl_xor(s, 16, 64);
    s += __shfl_xor(s, 32, 64);
    const float inv = 1.f / fmaxf((float)(ee - be), 1.f);
    ushort ru = *((const ushort*)gx2e + (size_t)n * GXST + 128 + o);
    float root = __uint_as_float(((uint)ru) << 16);
    float v = s * inv + root + lb2[o];
    float mx = v;
    #pragma unroll
    for (int off = 8; off >= 1; off >>= 1) mx = fmaxf(mx, __shfl_xor(mx, off, 64));
    float sm = __expf(v - mx);
    #pragma unroll
    for (int off = 8; off >= 1; off >>= 1) sm += __shfl_xor(sm, off, 64);
    if (kq == 0) out[(size_t)n * NC + o] = v - mx - __logf(sm);
  }
}

extern "C" void kernel_launch(void* const* d_in, const int* in_sizes, int n_in,
                              void* d_out, int out_size, void* d_ws, size_t ws_size,
                              hipStream_t stream) {
  const float* x     = (const float*)d_in[0];
  const int*   eidx  = (const int*)d_in[1];
  const float* eattr = (const float*)d_in[2];
  const float* g1w   = (const float*)d_in[3];
  const float* mu1   = (const float*)d_in[4];
  const float* sg1   = (const float*)d_in[5];
  const float* r1w   = (const float*)d_in[6];
  const float* b1    = (const float*)d_in[7];
  const float* g2w   = (const float*)d_in[8];
  const float* mu2   = (const float*)d_in[9];
  const float* sg2   = (const float*)d_in[10];
  const float* r2w   = (const float*)d_in[11];
  const float* b2    = (const float*)d_in[12];

  const int N = in_sizes[0] / NF;        // 50000
  const int E = in_sizes[1] / 2;         // 800000
  const int* row = eidx;
  const int* col = eidx + E;
  const int N2 = (N + 63) & ~63;         // 50048
  const int NP = (N + 1023) & ~1023;     // 50176
  const int NB = NP / 1024;              // 49

  uint4* ew1   = (uint4*)d_ws;                         // E
  uint4* ew2   = ew1 + (size_t)E;                      // E
  ushort* A1   = (ushort*)(ew2 + (size_t)E);           // N2*1152 (Z1|x)
  ushort* gx2e = A1;                                   // [N2,160] after gemm1
  ushort* h_bf = A1 + (size_t)N2 * 1152;               // N2*64
  ushort* W1t  = h_bf + (size_t)N2 * NH;               // 64*1152
  ushort* G2pT = W1t + (size_t)64 * 1152;              // 144*64
  int* erow    = (int*)(G2pT + (size_t)144 * 64);      // E
  int* counts  = erow + (size_t)E;                     // NP
  int* starts  = counts + NP;                          // NP
  int* cursor  = starts + NP;                          // NP
  int* bsums   = cursor + NP;                          // 64
  int* bofs    = bsums + 64;                           // 64

  hipMemsetAsync(counts, 0, (size_t)NP * sizeof(int), stream);
  hist_kernel<<<(E + 255) / 256, 256, 0, stream>>>(col, counts, E);
  scan1_kernel<<<NB, 256, 0, stream>>>(counts, starts, bsums);
  scan2_kernel<<<1, 64, 0, stream>>>(bsums, bofs, NB);
  scan3_kernel<<<NB, 256, 0, stream>>>(starts, cursor, bofs);
  fill_kernel<<<(E + 255) / 256, 256, 0, stream>>>(row, col, eattr, mu1, sg1,
                                                   mu2, sg2, cursor, erow,
                                                   ew1, ew2, E);
  cast_x_kernel<<<(N * 32 + 255) / 256, 256, 0, stream>>>(x, A1, N);
  prep_kernel<<<(64 * 1152 + 144 * 64 + 255) / 256, 256, 0, stream>>>(
      g1w, r1w, g2w, r2w, W1t, G2pT);

  z1_kernel<<<N / Z1NODES, 256, 0, stream>>>(A1, erow, ew1, starts, N);
  gemm1_mfma<<<N2 / 64, 256, 0, stream>>>(A1, W1t, b1, h_bf, N);
  gemm2a_kernel<<<N2 / 64, 256, 0, stream>>>(h_bf, G2pT, gx2e, N);
  edge2_kernel<<<(N + E2NODES - 1) / E2NODES, 256, 0, stream>>>(
      gx2e, erow, ew2, starts, b2, (float*)d_out, N);
}